// Round 9
// baseline (137.686 us; speedup 1.0000x reference)
//
#include <hip/hip_runtime.h>
#include <hip/hip_bf16.h>

typedef unsigned short u16;
typedef u16 u16x4 __attribute__((ext_vector_type(4)));
typedef u16 u16x8 __attribute__((ext_vector_type(8)));
typedef short s16x4 __attribute__((ext_vector_type(4)));
typedef __bf16 bf16x8 __attribute__((ext_vector_type(8)));
typedef float f32x4 __attribute__((ext_vector_type(4)));

static __device__ __forceinline__ u16 f2bf(float f) {
  return __builtin_bit_cast(u16, __float2bfloat16(f));   // RTNE; pairs into v_cvt_pk_bf16_f32
}

// async global->LDS, 16B per lane. LDS dest = wave-uniform base + lane*16.
static __device__ __forceinline__ void gload16(const u16* g, u16* l) {
  __builtin_amdgcn_global_load_lds(
      (const __attribute__((address_space(1))) unsigned*)g,
      (__attribute__((address_space(3))) unsigned*)l, 16, 0, 0);
}

#define WAIT8_BAR() asm volatile("s_waitcnt vmcnt(8)\ns_barrier" ::: "memory")
#define WAIT0_BAR() asm volatile("s_waitcnt vmcnt(0)\ns_barrier" ::: "memory")
#define BAR()       asm volatile("s_barrier" ::: "memory")

// ---------------- x f32 -> bf16 ----------------
__global__ __launch_bounds__(256) void cvt_x_kernel(const float* __restrict__ in,
                                                    u16* __restrict__ out) {
  int i = blockIdx.x * 256 + threadIdx.x;          // 8 elems per thread
  const float4* p = reinterpret_cast<const float4*>(in) + (size_t)i * 2;
  float4 a = p[0], b = p[1];
  u16x8 o;
  o[0] = f2bf(a.x); o[1] = f2bf(a.y); o[2] = f2bf(a.z); o[3] = f2bf(a.w);
  o[4] = f2bf(b.x); o[5] = f2bf(b.y); o[6] = f2bf(b.z); o[7] = f2bf(b.w);
  reinterpret_cast<u16x8*>(out)[i] = o;
}

// ---------------- W [768][2304] f32 -> WbT [2304][768] bf16 ----------------
__global__ __launch_bounds__(256) void cvt_wT_kernel(const float* __restrict__ W,
                                                     u16* __restrict__ WT) {
  int n  = blockIdx.x * 256 + threadIdx.x;   // 0..2303 (gridDim.x = 9)
  int k0 = blockIdx.y * 4;                   // gridDim.y = 192
  u16x4 o;
#pragma unroll
  for (int j = 0; j < 4; ++j) o[j] = f2bf(W[(size_t)(k0 + j) * 2304 + n]);
  *reinterpret_cast<u16x4*>(WT + (size_t)n * 768 + k0) = o;
}

// ---------------- QKV GEMM: [8192x768] @ [768x2304] + bias ----------------
// BK=64, both-sides XOR swizzle, 2-deep counted vmcnt(8) pipeline.
// q is pre-scaled by 0.125 (folded attention scale).
// writes q[bh][t][d], k[bh][t][d], vT[bh][d][t]  (all bf16)

static __device__ __forceinline__ void gemm_compute64(
    const u16* __restrict__ as, const u16* __restrict__ bs,
    int wm, int wn, int l16, int g, f32x4 (&acc)[4][4]) {
  bf16x8 af[4][2], bfr[4][2];
#pragma unroll
  for (int mi = 0; mi < 4; ++mi)
#pragma unroll
    for (int ks = 0; ks < 2; ++ks)
      af[mi][ks] = __builtin_bit_cast(bf16x8,
          *reinterpret_cast<const u16x8*>(
              as + (wm + mi * 16 + l16) * 64 + (((ks * 4 + g) ^ (l16 & 7)) * 8)));
#pragma unroll
  for (int ni = 0; ni < 4; ++ni)
#pragma unroll
    for (int ks = 0; ks < 2; ++ks)
      bfr[ni][ks] = __builtin_bit_cast(bf16x8,
          *reinterpret_cast<const u16x8*>(
              bs + (wn + ni * 16 + l16) * 64 + (((ks * 4 + g) ^ (l16 & 7)) * 8)));
#pragma unroll
  for (int ks = 0; ks < 2; ++ks)
#pragma unroll
    for (int mi = 0; mi < 4; ++mi)
#pragma unroll
      for (int ni = 0; ni < 4; ++ni)
        acc[mi][ni] = __builtin_amdgcn_mfma_f32_16x16x32_bf16(
            af[mi][ks], bfr[ni][ks], acc[mi][ni], 0, 0, 0);
}

__global__ __launch_bounds__(256, 2) void gemm_qkv_kernel(
    const u16* __restrict__ A, const u16* __restrict__ Bt,
    const float* __restrict__ bias,
    u16* __restrict__ qb, u16* __restrict__ kb, u16* __restrict__ vTb) {
  __shared__ __align__(16) u16 as0[128 * 64], as1[128 * 64];
  __shared__ __align__(16) u16 bs0[128 * 64], bs1[128 * 64];
  const int K = 768;
  int tid = threadIdx.x;
  int lane = tid & 63;
  int wave = tid >> 6;

  int m0 = blockIdx.x * 128;       // gridDim.x = 64 (m%8==XCD -> per-XCD L2-fit)
  int n0 = blockIdx.y * 128;       // gridDim.y = 18

  int wm = (wave >> 1) * 64;
  int wn = (wave & 1) * 64;
  int l16 = lane & 15, g = lane >> 4;

  // staging: wave w owns rows [w*32, w*32+32). Each instr covers 8 rows
  // (8 lanes/row x 16B). Lane reads global chunk (l&7)^((l>>3)&7) so the
  // linear LDS dest receives the swizzled layout (rule #21).
  int r8 = lane >> 3;
  int cs = (lane & 7) ^ (r8 & 7);
  const u16* gA = A  + (size_t)(m0 + wave * 32 + r8) * K + cs * 8;
  const u16* gB = Bt + (size_t)(n0 + wave * 32 + r8) * K + cs * 8;
  int lofs = wave * 2048;   // elems (32 rows x 64); +512/instr (8 rows)

  f32x4 acc[4][4];
#pragma unroll
  for (int mi = 0; mi < 4; ++mi)
#pragma unroll
    for (int ni = 0; ni < 4; ++ni) acc[mi][ni] = (f32x4){0.f, 0.f, 0.f, 0.f};

#define STAGE(Abuf, Bbuf, kk)                              \
  do {                                                     \
    gload16(gA + (kk),           Abuf + lofs);             \
    gload16(gA + (kk) +  8 * K,  Abuf + lofs + 512);       \
    gload16(gA + (kk) + 16 * K,  Abuf + lofs + 1024);      \
    gload16(gA + (kk) + 24 * K,  Abuf + lofs + 1536);      \
    gload16(gB + (kk),           Bbuf + lofs);             \
    gload16(gB + (kk) +  8 * K,  Bbuf + lofs + 512);       \
    gload16(gB + (kk) + 16 * K,  Bbuf + lofs + 1024);      \
    gload16(gB + (kk) + 24 * K,  Bbuf + lofs + 1536);      \
  } while (0)

  // prologue: chunks 0,1 in flight (16 loads)
  STAGE(as0, bs0, 0);
  STAGE(as1, bs1, 64);
  for (int j = 0; j < 5; ++j) {
    int k0 = j * 128;
    WAIT8_BAR();                        // chunk 2j landed; newest 8 in flight
    gemm_compute64(as0, bs0, wm, wn, l16, g, acc);
    BAR();
    STAGE(as0, bs0, k0 + 128);
    WAIT8_BAR();                        // chunk 2j+1 landed
    gemm_compute64(as1, bs1, wm, wn, l16, g, acc);
    BAR();
    STAGE(as1, bs1, k0 + 192);
  }
  // peel: chunks k=640 (as0), k=704 (as1)
  WAIT8_BAR();
  gemm_compute64(as0, bs0, wm, wn, l16, g, acc);
  WAIT0_BAR();
  gemm_compute64(as1, bs1, wm, wn, l16, g, acc);
#undef STAGE

  // epilogue: bias + scatter to q/k/vT (bf16). q gets *0.125 (attn scale).
  int tbase = m0 & 1023;
  int b = m0 >> 10;
  int g4 = g * 4;
#pragma unroll
  for (int ni = 0; ni < 4; ++ni) {
    int n = n0 + wn + ni * 16 + l16;
    float bv = bias[n];
    int region = n / 768;
    float scl = (region == 0) ? 0.125f : 1.0f;
    float bvs = bv * scl;
    int c = n - region * 768;
    int h = c >> 6, d = c & 63;
    int bh = b * 12 + h;
#pragma unroll
    for (int mi = 0; mi < 4; ++mi) {
      int t0 = tbase + wm + mi * 16 + g4;
      if (region == 2) {
        u16x4 pv;
#pragma unroll
        for (int r = 0; r < 4; ++r) pv[r] = f2bf(acc[mi][ni][r] + bv);
        *reinterpret_cast<u16x4*>(vTb + ((size_t)bh * 64 + d) * 1024 + t0) = pv;
      } else {
        u16* dst = (region == 0) ? qb : kb;
#pragma unroll
        for (int r = 0; r < 4; ++r)
          dst[((size_t)bh * 1024 + t0 + r) * 64 + d] = f2bf(fmaf(acc[mi][ni][r], scl, bvs));
      }
    }
  }
}

// ---------------- causal relu attention (zero-LDS) ----------------
// y[b,h,q,:] = sum_{k<=q} relu(q.k) * v[k]   (scale pre-folded into q)
// Swapped QK^T: s2[kj][qi] lane(l16,g) reg r = S^T[key=16kj+4g+r][q=l16]
//  == B-fragment of mfma_f32_16x16x16_bf16. PV: Y^T[d][q] += mfma(A=V^T, B=P)
// entirely in registers — no LDS round-trip. Diag tile peeled (mask-free main loop).
__global__ __launch_bounds__(256) void attn_kernel(
    const u16* __restrict__ qb, const u16* __restrict__ kb,
    const u16* __restrict__ vTb, float* __restrict__ out) {
  int lane = threadIdx.x & 63;
  int wave = threadIdx.x >> 6;
  int bh = blockIdx.x;                           // 0..95
  int q0 = (7 - blockIdx.y) * 128 + wave * 32;   // heaviest blocks first
  int b = bh / 12, h = bh - b * 12;
  const u16* Q  = qb  + (size_t)bh * 65536;
  const u16* Kp = kb  + (size_t)bh * 65536;
  const u16* Vt = vTb + (size_t)bh * 65536;
  int l16 = lane & 15, g = lane >> 4;

  bf16x8 qf[2][2];
#pragma unroll
  for (int qi = 0; qi < 2; ++qi)
#pragma unroll
    for (int ks = 0; ks < 2; ++ks)
      qf[qi][ks] = __builtin_bit_cast(bf16x8,
          *reinterpret_cast<const u16x8*>(Q + (q0 + qi * 16 + l16) * 64 + ks * 32 + g * 8));

  // Y^T accumulators: yT[qi][ni] lane(l16,g) reg r = Y^T[d=ni*16+g*4+r][q=qi*16+l16]
  f32x4 yT[2][4];
#pragma unroll
  for (int qi = 0; qi < 2; ++qi)
#pragma unroll
    for (int ni = 0; ni < 4; ++ni) yT[qi][ni] = (f32x4){0.f, 0.f, 0.f, 0.f};

  int ntile = (q0 >> 6) + 1;             // 64-key tiles
  int qoff = q0 & 63;                    // 0 or 32

  // prologue: K(0) fragments, S^T(0)
  u16x8 kn[4][2];
#pragma unroll
  for (int kj = 0; kj < 4; ++kj)
#pragma unroll
    for (int ks = 0; ks < 2; ++ks)
      kn[kj][ks] = *reinterpret_cast<const u16x8*>(
          Kp + (kj * 16 + l16) * 64 + ks * 32 + g * 8);

  f32x4 s2[4][2];
#pragma unroll
  for (int kj = 0; kj < 4; ++kj)
#pragma unroll
    for (int qi = 0; qi < 2; ++qi) s2[kj][qi] = (f32x4){0.f, 0.f, 0.f, 0.f};
#pragma unroll
  for (int ks = 0; ks < 2; ++ks)
#pragma unroll
    for (int kj = 0; kj < 4; ++kj)
#pragma unroll
      for (int qi = 0; qi < 2; ++qi)
        s2[kj][qi] = __builtin_amdgcn_mfma_f32_16x16x32_bf16(
            __builtin_bit_cast(bf16x8, kn[kj][ks]), qf[qi][ks], s2[kj][qi], 0, 0, 0);

  for (int kt = 0; kt < ntile; ++kt) {
    int kb0 = kt << 6;
    bool last = (kt == ntile - 1);

    // 1) V^T A-fragments for this tile: lane(l16,g) holds V^T[d=ni*16+l16][key=16kj+4g..+3]
    u16x4 va[4][4];   // [ni][kj]
#pragma unroll
    for (int ni = 0; ni < 4; ++ni)
#pragma unroll
      for (int kj = 0; kj < 4; ++kj)
        va[ni][kj] = *reinterpret_cast<const u16x4*>(
            Vt + (ni * 16 + l16) * 1024 + kb0 + kj * 16 + g * 4);

    // 2) K(t+1) loads
    if (!last) {
      int kb2 = kb0 + 64;
#pragma unroll
      for (int kj = 0; kj < 4; ++kj)
#pragma unroll
        for (int ks = 0; ks < 2; ++ks)
          kn[kj][ks] = *reinterpret_cast<const u16x8*>(
              Kp + (kb2 + kj * 16 + l16) * 64 + ks * 32 + g * 8);
    }

    // 3) pack P(t) in-register: relu (+ diag mask on peeled last tile)
    s16x4 pb[4][2];
    if (last) {
#pragma unroll
      for (int kj = 0; kj < 4; ++kj)
#pragma unroll
        for (int qi = 0; qi < 2; ++qi) {
          u16x4 pv;
#pragma unroll
          for (int r = 0; r < 4; ++r) {
            float v = fmaxf(s2[kj][qi][r], 0.f);
            if (kj * 16 + g * 4 + r > qoff + qi * 16 + l16) v = 0.f;
            pv[r] = f2bf(v);
          }
          pb[kj][qi] = __builtin_bit_cast(s16x4, pv);
        }
    } else {
#pragma unroll
      for (int kj = 0; kj < 4; ++kj)
#pragma unroll
        for (int qi = 0; qi < 2; ++qi) {
          u16x4 pv;
#pragma unroll
          for (int r = 0; r < 4; ++r) pv[r] = f2bf(fmaxf(s2[kj][qi][r], 0.f));
          pb[kj][qi] = __builtin_bit_cast(s16x4, pv);
        }
    }

    __builtin_amdgcn_s_setprio(1);
    // 4) QK^T(t+1) — overwrites s2 (pb already extracted)
    if (!last) {
#pragma unroll
      for (int kj = 0; kj < 4; ++kj)
#pragma unroll
        for (int qi = 0; qi < 2; ++qi) s2[kj][qi] = (f32x4){0.f, 0.f, 0.f, 0.f};
#pragma unroll
      for (int ks = 0; ks < 2; ++ks)
#pragma unroll
        for (int kj = 0; kj < 4; ++kj)
#pragma unroll
          for (int qi = 0; qi < 2; ++qi)
            s2[kj][qi] = __builtin_amdgcn_mfma_f32_16x16x32_bf16(
                __builtin_bit_cast(bf16x8, kn[kj][ks]), qf[qi][ks], s2[kj][qi], 0, 0, 0);
    }

    // 5) PV(t): Y^T += V^T @ P  (16x16x16, B = pb in registers)
#pragma unroll
    for (int qi = 0; qi < 2; ++qi)
#pragma unroll
      for (int ni = 0; ni < 4; ++ni)
#pragma unroll
        for (int kj = 0; kj < 4; ++kj)
          yT[qi][ni] = __builtin_amdgcn_mfma_f32_16x16x16bf16_1k(
              __builtin_bit_cast(s16x4, va[ni][kj]), pb[kj][qi], yT[qi][ni], 0, 0, 0);
    __builtin_amdgcn_s_setprio(0);
  }

  // out[b, q, h*64+d] f32: contiguous f32x4 per (qi,ni)
  float* outp = out + (size_t)b * 1024 * 768 + (size_t)h * 64;
#pragma unroll
  for (int qi = 0; qi < 2; ++qi) {
    int q = q0 + qi * 16 + l16;
#pragma unroll
    for (int ni = 0; ni < 4; ++ni)
      *reinterpret_cast<f32x4*>(outp + (size_t)q * 768 + ni * 16 + g * 4) = yT[qi][ni];
  }
}

extern "C" void kernel_launch(void* const* d_in, const int* in_sizes, int n_in,
                              void* d_out, int out_size, void* d_ws, size_t ws_size,
                              hipStream_t stream) {
  const float* x    = (const float*)d_in[0];
  const float* W    = (const float*)d_in[1];
  const float* bias = (const float*)d_in[2];
  float* out = (float*)d_out;
  char* ws = (char*)d_ws;

  // ws layout (bytes): xb 12.58MB | WbT 3.54MB | qb 12.58MB | kb 12.58MB | vTb 12.58MB
  u16* xb  = (u16*)(ws);
  u16* WbT = (u16*)(ws + 12582912);
  u16* qb  = (u16*)(ws + 16121856);
  u16* kb  = (u16*)(ws + 28704768);
  u16* vTb = (u16*)(ws + 41287680);

  hipLaunchKernelGGL(cvt_x_kernel, dim3(3072), dim3(256), 0, stream, x, xb);
  hipLaunchKernelGGL(cvt_wT_kernel, dim3(9, 192), dim3(256), 0, stream, W, WbT);
  hipLaunchKernelGGL(gemm_qkv_kernel, dim3(64, 18), dim3(256), 0, stream,
                     xb, WbT, bias, qb, kb, vTb);
  hipLaunchKernelGGL(attn_kernel, dim3(96, 8), dim3(256), 0, stream, qb, kb, vTb, out);
}

// Round 10
// 82.014 us; speedup vs baseline: 1.6788x; 1.6788x over previous
//
#include <hip/hip_runtime.h>
#include <hip/hip_bf16.h>

typedef unsigned short u16;
typedef u16 u16x4 __attribute__((ext_vector_type(4)));
typedef u16 u16x8 __attribute__((ext_vector_type(8)));
typedef __bf16 bf16x8 __attribute__((ext_vector_type(8)));
typedef float f32x4 __attribute__((ext_vector_type(4)));

static __device__ __forceinline__ u16 f2bf(float f) {
  return __builtin_bit_cast(u16, __float2bfloat16(f));   // RTNE; pairs into v_cvt_pk_bf16_f32
}

// async global->LDS, 16B per lane. LDS dest = wave-uniform base + lane*16.
static __device__ __forceinline__ void gload16(const u16* g, u16* l) {
  __builtin_amdgcn_global_load_lds(
      (const __attribute__((address_space(1))) unsigned*)g,
      (__attribute__((address_space(3))) unsigned*)l, 16, 0, 0);
}

#define WAIT8_BAR() asm volatile("s_waitcnt vmcnt(8)\ns_barrier" ::: "memory")
#define WAIT0_BAR() asm volatile("s_waitcnt vmcnt(0)\ns_barrier" ::: "memory")
#define BAR()       asm volatile("s_barrier" ::: "memory")

// ---------------- x f32 -> bf16 ----------------
__global__ __launch_bounds__(256) void cvt_x_kernel(const float* __restrict__ in,
                                                    u16* __restrict__ out) {
  int i = blockIdx.x * 256 + threadIdx.x;          // 8 elems per thread
  const float4* p = reinterpret_cast<const float4*>(in) + (size_t)i * 2;
  float4 a = p[0], b = p[1];
  u16x8 o;
  o[0] = f2bf(a.x); o[1] = f2bf(a.y); o[2] = f2bf(a.z); o[3] = f2bf(a.w);
  o[4] = f2bf(b.x); o[5] = f2bf(b.y); o[6] = f2bf(b.z); o[7] = f2bf(b.w);
  reinterpret_cast<u16x8*>(out)[i] = o;
}

// ---------------- W [768][2304] f32 -> WbT [2304][768] bf16 ----------------
__global__ __launch_bounds__(256) void cvt_wT_kernel(const float* __restrict__ W,
                                                     u16* __restrict__ WT) {
  int n  = blockIdx.x * 256 + threadIdx.x;   // 0..2303 (gridDim.x = 9)
  int k0 = blockIdx.y * 4;                   // gridDim.y = 192
  u16x4 o;
#pragma unroll
  for (int j = 0; j < 4; ++j) o[j] = f2bf(W[(size_t)(k0 + j) * 2304 + n]);
  *reinterpret_cast<u16x4*>(WT + (size_t)n * 768 + k0) = o;
}

// ---------------- QKV GEMM: [8192x768] @ [768x2304] + bias ----------------
// BK=64, both-sides XOR swizzle, 2-deep counted vmcnt(8) pipeline.
// q is pre-scaled by 0.125 (folded attention scale).
// writes q[bh][t][d], k[bh][t][d], vT[bh][d][t]  (all bf16)

static __device__ __forceinline__ void gemm_compute64(
    const u16* __restrict__ as, const u16* __restrict__ bs,
    int wm, int wn, int l16, int g, f32x4 (&acc)[4][4]) {
  bf16x8 af[4][2], bfr[4][2];
#pragma unroll
  for (int mi = 0; mi < 4; ++mi)
#pragma unroll
    for (int ks = 0; ks < 2; ++ks)
      af[mi][ks] = __builtin_bit_cast(bf16x8,
          *reinterpret_cast<const u16x8*>(
              as + (wm + mi * 16 + l16) * 64 + (((ks * 4 + g) ^ (l16 & 7)) * 8)));
#pragma unroll
  for (int ni = 0; ni < 4; ++ni)
#pragma unroll
    for (int ks = 0; ks < 2; ++ks)
      bfr[ni][ks] = __builtin_bit_cast(bf16x8,
          *reinterpret_cast<const u16x8*>(
              bs + (wn + ni * 16 + l16) * 64 + (((ks * 4 + g) ^ (l16 & 7)) * 8)));
#pragma unroll
  for (int ks = 0; ks < 2; ++ks)
#pragma unroll
    for (int mi = 0; mi < 4; ++mi)
#pragma unroll
      for (int ni = 0; ni < 4; ++ni)
        acc[mi][ni] = __builtin_amdgcn_mfma_f32_16x16x32_bf16(
            af[mi][ks], bfr[ni][ks], acc[mi][ni], 0, 0, 0);
}

__global__ __launch_bounds__(256, 2) void gemm_qkv_kernel(
    const u16* __restrict__ A, const u16* __restrict__ Bt,
    const float* __restrict__ bias,
    u16* __restrict__ qb, u16* __restrict__ kb, u16* __restrict__ vTb) {
  __shared__ __align__(16) u16 as0[128 * 64], as1[128 * 64];
  __shared__ __align__(16) u16 bs0[128 * 64], bs1[128 * 64];
  const int K = 768;
  int tid = threadIdx.x;
  int lane = tid & 63;
  int wave = tid >> 6;

  int m0 = blockIdx.x * 128;       // gridDim.x = 64 (m%8==XCD -> per-XCD L2-fit)
  int n0 = blockIdx.y * 128;       // gridDim.y = 18

  int wm = (wave >> 1) * 64;
  int wn = (wave & 1) * 64;
  int l16 = lane & 15, g = lane >> 4;

  int r8 = lane >> 3;
  int cs = (lane & 7) ^ (r8 & 7);
  const u16* gA = A  + (size_t)(m0 + wave * 32 + r8) * K + cs * 8;
  const u16* gB = Bt + (size_t)(n0 + wave * 32 + r8) * K + cs * 8;
  int lofs = wave * 2048;

  f32x4 acc[4][4];
#pragma unroll
  for (int mi = 0; mi < 4; ++mi)
#pragma unroll
    for (int ni = 0; ni < 4; ++ni) acc[mi][ni] = (f32x4){0.f, 0.f, 0.f, 0.f};

#define STAGE(Abuf, Bbuf, kk)                              \
  do {                                                     \
    gload16(gA + (kk),           Abuf + lofs);             \
    gload16(gA + (kk) +  8 * K,  Abuf + lofs + 512);       \
    gload16(gA + (kk) + 16 * K,  Abuf + lofs + 1024);      \
    gload16(gA + (kk) + 24 * K,  Abuf + lofs + 1536);      \
    gload16(gB + (kk),           Bbuf + lofs);             \
    gload16(gB + (kk) +  8 * K,  Bbuf + lofs + 512);       \
    gload16(gB + (kk) + 16 * K,  Bbuf + lofs + 1024);      \
    gload16(gB + (kk) + 24 * K,  Bbuf + lofs + 1536);      \
  } while (0)

  STAGE(as0, bs0, 0);
  STAGE(as1, bs1, 64);
  for (int j = 0; j < 5; ++j) {
    int k0 = j * 128;
    WAIT8_BAR();
    gemm_compute64(as0, bs0, wm, wn, l16, g, acc);
    BAR();
    STAGE(as0, bs0, k0 + 128);
    WAIT8_BAR();
    gemm_compute64(as1, bs1, wm, wn, l16, g, acc);
    BAR();
    STAGE(as1, bs1, k0 + 192);
  }
  WAIT8_BAR();
  gemm_compute64(as0, bs0, wm, wn, l16, g, acc);
  WAIT0_BAR();
  gemm_compute64(as1, bs1, wm, wn, l16, g, acc);
#undef STAGE

  // epilogue: bias + scatter to q/k/vT (bf16). q gets *0.125 (attn scale).
  int tbase = m0 & 1023;
  int b = m0 >> 10;
  int g4 = g * 4;
#pragma unroll
  for (int ni = 0; ni < 4; ++ni) {
    int n = n0 + wn + ni * 16 + l16;
    float bv = bias[n];
    int region = n / 768;
    float scl = (region == 0) ? 0.125f : 1.0f;
    float bvs = bv * scl;
    int c = n - region * 768;
    int h = c >> 6, d = c & 63;
    int bh = b * 12 + h;
#pragma unroll
    for (int mi = 0; mi < 4; ++mi) {
      int t0 = tbase + wm + mi * 16 + g4;
      if (region == 2) {
        u16x4 pv;
#pragma unroll
        for (int r = 0; r < 4; ++r) pv[r] = f2bf(acc[mi][ni][r] + bv);
        *reinterpret_cast<u16x4*>(vTb + ((size_t)bh * 64 + d) * 1024 + t0) = pv;
      } else {
        u16* dst = (region == 0) ? qb : kb;
#pragma unroll
        for (int r = 0; r < 4; ++r)
          dst[((size_t)bh * 1024 + t0 + r) * 64 + d] = f2bf(fmaf(acc[mi][ni][r], scl, bvs));
      }
    }
  }
}

// ---------------- causal relu attention (block-shared K/V staging) ----------------
// y[b,h,q,:] = sum_{k<=q} relu(q.k) * v[k]   (scale pre-folded into q)
// Block = 4 waves, same head, q-groups qbase+{0,32,64,96}. K/V 64-key tiles
// staged once per block into double-buffered LDS via global_load_lds (4x L2
// traffic cut), XOR-chunk swizzle (both-sides). One vmcnt(0)+barrier per tile.
// Compute = r7's verified fragments: swapped QK^T, P via per-wave LDS, PV 16x16x32.
__global__ __launch_bounds__(256, 3) void attn_kernel(
    const u16* __restrict__ qb, const u16* __restrict__ kb,
    const u16* __restrict__ vTb, float* __restrict__ out) {
  __shared__ __align__(16) u16 kbuf0[64 * 64], kbuf1[64 * 64];
  __shared__ __align__(16) u16 vbuf0[64 * 64], vbuf1[64 * 64];
  __shared__ __align__(16) u16 plds[4][32 * 72];
  int lane = threadIdx.x & 63;
  int wave = threadIdx.x >> 6;
  int bh = blockIdx.x;                           // 0..95
  int qbase = (7 - blockIdx.y) * 128;            // heaviest blocks first
  int q0 = qbase + wave * 32;
  int b = bh / 12, h = bh - b * 12;
  const u16* Q  = qb  + (size_t)bh * 65536;
  const u16* Kp = kb  + (size_t)bh * 65536;
  const u16* Vt = vTb + (size_t)bh * 65536;
  int l16 = lane & 15, g = lane >> 4;
  u16* pw = &plds[wave][0];

  int ntw = (q0 >> 6) + 1;        // this wave's active tiles
  int ntB = (qbase >> 6) + 2;     // block-uniform loop bound (= ntw of wave 3)
  int qoff = q0 & 63;             // 0 or 32

  // staging addresses: wave stages K rows [16w,16w+16) and V^T rows [16w,16w+16)
  // of each tile; lane l covers row (l>>3) within its 8-row instr, global chunk
  // (l&7)^((l>>3)&7) so the linear LDS dest receives the swizzled layout.
  int r8q = lane >> 3;
  int csw = (lane & 7) ^ (r8q & 7);
  const u16* kSrc = Kp + (size_t)(wave * 16 + r8q) * 64 + csw * 8;
  const u16* vSrc = Vt + (size_t)(wave * 16 + r8q) * 1024 + csw * 8;
  int sofs = wave * 1024;   // LDS elems (2 instrs x 512)

#define ASTAGE(kbuf, vbuf, kbase)                                   \
  do {                                                              \
    gload16(kSrc + (size_t)(kbase) * 64,       kbuf + sofs);        \
    gload16(kSrc + (size_t)((kbase) + 8) * 64, kbuf + sofs + 512);  \
    gload16(vSrc + (kbase),                    vbuf + sofs);        \
    gload16(vSrc + (kbase) + 8 * 1024,         vbuf + sofs + 512);  \
  } while (0)

  bf16x8 qf[2][2];
#pragma unroll
  for (int qi = 0; qi < 2; ++qi)
#pragma unroll
    for (int ks = 0; ks < 2; ++ks)
      qf[qi][ks] = __builtin_bit_cast(bf16x8,
          *reinterpret_cast<const u16x8*>(Q + (q0 + qi * 16 + l16) * 64 + ks * 32 + g * 8));

  f32x4 y[2][4];
#pragma unroll
  for (int mi = 0; mi < 2; ++mi)
#pragma unroll
    for (int ni = 0; ni < 4; ++ni) y[mi][ni] = (f32x4){0.f, 0.f, 0.f, 0.f};

  // prologue: stage tile 0
  ASTAGE(kbuf0, vbuf0, 0);
  WAIT0_BAR();

  for (int kt = 0; kt < ntB; ++kt) {
    u16 *kcur, *vcur, *knx, *vnx;
    if (kt & 1) { kcur = kbuf1; vcur = vbuf1; knx = kbuf0; vnx = vbuf0; }
    else        { kcur = kbuf0; vcur = vbuf0; knx = kbuf1; vnx = vbuf1; }

    // stage next tile while computing current
    if (kt + 1 < ntB) ASTAGE(knx, vnx, (kt + 1) << 6);

    if (kt < ntw) {
      // K fragments from LDS (swizzled read)
      bf16x8 kf[4][2];
#pragma unroll
      for (int kj = 0; kj < 4; ++kj)
#pragma unroll
        for (int ks = 0; ks < 2; ++ks)
          kf[kj][ks] = __builtin_bit_cast(bf16x8,
              *reinterpret_cast<const u16x8*>(
                  kcur + (kj * 16 + l16) * 64 + (((ks * 4 + g) ^ (l16 & 7)) * 8)));

      // QK^T: s2[kj][qi] lane(l16,g) reg r = S^T[key=16kj+4g+r][q=qi*16+l16]
      f32x4 s2[4][2];
#pragma unroll
      for (int kj = 0; kj < 4; ++kj)
#pragma unroll
        for (int qi = 0; qi < 2; ++qi) s2[kj][qi] = (f32x4){0.f, 0.f, 0.f, 0.f};
      __builtin_amdgcn_s_setprio(1);
#pragma unroll
      for (int ks = 0; ks < 2; ++ks)
#pragma unroll
        for (int kj = 0; kj < 4; ++kj)
#pragma unroll
          for (int qi = 0; qi < 2; ++qi)
            s2[kj][qi] = __builtin_amdgcn_mfma_f32_16x16x32_bf16(
                kf[kj][ks], qf[qi][ks], s2[kj][qi], 0, 0, 0);
      __builtin_amdgcn_s_setprio(0);

      // pack P: relu (+ diag mask only on this wave's last tile); LDS write
      if (kt == ntw - 1) {
#pragma unroll
        for (int kj = 0; kj < 4; ++kj)
#pragma unroll
          for (int qi = 0; qi < 2; ++qi) {
            u16x4 pv;
#pragma unroll
            for (int r = 0; r < 4; ++r) {
              float v = fmaxf(s2[kj][qi][r], 0.f);
              if (kj * 16 + g * 4 + r > qoff + qi * 16 + l16) v = 0.f;
              pv[r] = f2bf(v);
            }
            *reinterpret_cast<u16x4*>(pw + (qi * 16 + l16) * 72 + kj * 16 + g * 4) = pv;
          }
      } else {
#pragma unroll
        for (int kj = 0; kj < 4; ++kj)
#pragma unroll
          for (int qi = 0; qi < 2; ++qi) {
            u16x4 pv;
#pragma unroll
            for (int r = 0; r < 4; ++r) pv[r] = f2bf(fmaxf(s2[kj][qi][r], 0.f));
            *reinterpret_cast<u16x4*>(pw + (qi * 16 + l16) * 72 + kj * 16 + g * 4) = pv;
          }
      }

      // V fragments from LDS (fills P write->read latency window)
      bf16x8 vf[4][2];
#pragma unroll
      for (int ni = 0; ni < 4; ++ni)
#pragma unroll
        for (int kc = 0; kc < 2; ++kc)
          vf[ni][kc] = __builtin_bit_cast(bf16x8,
              *reinterpret_cast<const u16x8*>(
                  vcur + (ni * 16 + l16) * 64 + (((kc * 4 + g) ^ (l16 & 7)) * 8)));

      // read P, PV
      bf16x8 pa[2][2];
#pragma unroll
      for (int mi = 0; mi < 2; ++mi)
#pragma unroll
        for (int kc = 0; kc < 2; ++kc)
          pa[mi][kc] = __builtin_bit_cast(bf16x8,
              *reinterpret_cast<const u16x8*>(pw + (mi * 16 + l16) * 72 + kc * 32 + g * 8));
      __builtin_amdgcn_s_setprio(1);
#pragma unroll
      for (int kc = 0; kc < 2; ++kc)
#pragma unroll
        for (int ni = 0; ni < 4; ++ni)
#pragma unroll
          for (int mi = 0; mi < 2; ++mi)
            y[mi][ni] = __builtin_amdgcn_mfma_f32_16x16x32_bf16(
                pa[mi][kc], vf[ni][kc], y[mi][ni], 0, 0, 0);
      __builtin_amdgcn_s_setprio(0);
    }

    WAIT0_BAR();   // my stage loads landed + all waves done reading cur
  }
#undef ASTAGE

  // out[b, t, h*64+d] f32
  float* outp = out + (size_t)b * 1024 * 768 + (size_t)h * 64;
#pragma unroll
  for (int mi = 0; mi < 2; ++mi)
#pragma unroll
    for (int r = 0; r < 4; ++r) {
      int t = q0 + mi * 16 + g * 4 + r;
#pragma unroll
      for (int ni = 0; ni < 4; ++ni)
        outp[(size_t)t * 768 + ni * 16 + l16] = y[mi][ni][r];
    }
}

extern "C" void kernel_launch(void* const* d_in, const int* in_sizes, int n_in,
                              void* d_out, int out_size, void* d_ws, size_t ws_size,
                              hipStream_t stream) {
  const float* x    = (const float*)d_in[0];
  const float* W    = (const float*)d_in[1];
  const float* bias = (const float*)d_in[2];
  float* out = (float*)d_out;
  char* ws = (char*)d_ws;

  // ws layout (bytes): xb 12.58MB | WbT 3.54MB | qb 12.58MB | kb 12.58MB | vTb 12.58MB
  u16* xb  = (u16*)(ws);
  u16* WbT = (u16*)(ws + 12582912);
  u16* qb  = (u16*)(ws + 16121856);
  u16* kb  = (u16*)(ws + 28704768);
  u16* vTb = (u16*)(ws + 41287680);

  hipLaunchKernelGGL(cvt_x_kernel, dim3(3072), dim3(256), 0, stream, x, xb);
  hipLaunchKernelGGL(cvt_wT_kernel, dim3(9, 192), dim3(256), 0, stream, W, WbT);
  hipLaunchKernelGGL(gemm_qkv_kernel, dim3(64, 18), dim3(256), 0, stream,
                     xb, WbT, bias, qb, kb, vTb);
  hipLaunchKernelGGL(attn_kernel, dim3(96, 8), dim3(256), 0, stream, qb, kb, vTb, out);
}

// Round 13
// 80.428 us; speedup vs baseline: 1.7119x; 1.0197x over previous
//
#include <hip/hip_runtime.h>
#include <hip/hip_bf16.h>

typedef unsigned short u16;
typedef u16 u16x4 __attribute__((ext_vector_type(4)));
typedef u16 u16x8 __attribute__((ext_vector_type(8)));
typedef __bf16 bf16x8 __attribute__((ext_vector_type(8)));
typedef float f32x4 __attribute__((ext_vector_type(4)));

static __device__ __forceinline__ u16 f2bf(float f) {
  return __builtin_bit_cast(u16, __float2bfloat16(f));   // RTNE; pairs into v_cvt_pk_bf16_f32
}

// async global->LDS, 16B per lane. LDS dest = wave-uniform base + lane*16.
static __device__ __forceinline__ void gload16(const u16* g, u16* l) {
  __builtin_amdgcn_global_load_lds(
      (const __attribute__((address_space(1))) unsigned*)g,
      (__attribute__((address_space(3))) unsigned*)l, 16, 0, 0);
}

// Barriers guarding LDS buffer handoff MUST drain lgkmcnt inside the asm:
// hipcc can sink register-only MFMAs below an asm s_barrier ("memory" doesn't
// order them), leaving their feeding ds_reads outstanding across the barrier
// while another wave's global_load_lds DMA overwrites the buffer (rule #18).
#define WAIT8_BAR() asm volatile("s_waitcnt vmcnt(8) lgkmcnt(0)\ns_barrier" ::: "memory")
#define WAIT0_BAR() asm volatile("s_waitcnt vmcnt(0) lgkmcnt(0)\ns_barrier" ::: "memory")
#define BAR()       asm volatile("s_waitcnt lgkmcnt(0)\ns_barrier" ::: "memory")

// ---------------- x f32 -> bf16 ----------------
__global__ __launch_bounds__(256) void cvt_x_kernel(const float* __restrict__ in,
                                                    u16* __restrict__ out) {
  int i = blockIdx.x * 256 + threadIdx.x;          // 8 elems per thread
  const float4* p = reinterpret_cast<const float4*>(in) + (size_t)i * 2;
  float4 a = p[0], b = p[1];
  u16x8 o;
  o[0] = f2bf(a.x); o[1] = f2bf(a.y); o[2] = f2bf(a.z); o[3] = f2bf(a.w);
  o[4] = f2bf(b.x); o[5] = f2bf(b.y); o[6] = f2bf(b.z); o[7] = f2bf(b.w);
  reinterpret_cast<u16x8*>(out)[i] = o;
}

// ---------------- W [768][2304] f32 -> WbT [2304][768] bf16 ----------------
__global__ __launch_bounds__(256) void cvt_wT_kernel(const float* __restrict__ W,
                                                     u16* __restrict__ WT) {
  int n  = blockIdx.x * 256 + threadIdx.x;   // 0..2303 (gridDim.x = 9)
  int k0 = blockIdx.y * 4;                   // gridDim.y = 192
  u16x4 o;
#pragma unroll
  for (int j = 0; j < 4; ++j) o[j] = f2bf(W[(size_t)(k0 + j) * 2304 + n]);
  *reinterpret_cast<u16x4*>(WT + (size_t)n * 768 + k0) = o;
}

// ---------------- QKV GEMM: [8192x768] @ [768x2304] + bias ----------------
// BK=64, both-sides XOR swizzle, 2-deep counted vmcnt(8) pipeline.
// XCD panel-sequential remap (A panel L2-resident). LDS-transpose epilogue
// (stride 72 elems = 144B rows -> 16B-aligned b128 readback) for coalesced q/k.
// q is pre-scaled by 0.125. writes q[bh][t][d], k[bh][t][d], vT[bh][d][t].

static __device__ __forceinline__ void gemm_compute64(
    const u16* __restrict__ as, const u16* __restrict__ bs,
    int wm, int wn, int l16, int g, f32x4 (&acc)[4][4]) {
  bf16x8 af[4][2], bfr[4][2];
#pragma unroll
  for (int mi = 0; mi < 4; ++mi)
#pragma unroll
    for (int ks = 0; ks < 2; ++ks)
      af[mi][ks] = __builtin_bit_cast(bf16x8,
          *reinterpret_cast<const u16x8*>(
              as + (wm + mi * 16 + l16) * 64 + (((ks * 4 + g) ^ (l16 & 7)) * 8)));
#pragma unroll
  for (int ni = 0; ni < 4; ++ni)
#pragma unroll
    for (int ks = 0; ks < 2; ++ks)
      bfr[ni][ks] = __builtin_bit_cast(bf16x8,
          *reinterpret_cast<const u16x8*>(
              bs + (wn + ni * 16 + l16) * 64 + (((ks * 4 + g) ^ (l16 & 7)) * 8)));
#pragma unroll
  for (int ks = 0; ks < 2; ++ks)
#pragma unroll
    for (int mi = 0; mi < 4; ++mi)
#pragma unroll
      for (int ni = 0; ni < 4; ++ni)
        acc[mi][ni] = __builtin_amdgcn_mfma_f32_16x16x32_bf16(
            af[mi][ks], bfr[ni][ks], acc[mi][ni], 0, 0, 0);
}

__global__ __launch_bounds__(256, 2) void gemm_qkv_kernel(
    const u16* __restrict__ A, const u16* __restrict__ Bt,
    const float* __restrict__ bias,
    u16* __restrict__ qb, u16* __restrict__ kb, u16* __restrict__ vTb) {
  __shared__ __align__(16) u16 smem[4 * 128 * 64];   // 64 KB: as0|as1|bs0|bs1
  u16* as0 = smem;
  u16* as1 = smem + 128 * 64;
  u16* bs0 = smem + 2 * 128 * 64;
  u16* bs1 = smem + 3 * 128 * 64;
  const int K = 768;
  int tid = threadIdx.x;
  int lane = tid & 63;
  int wave = tid >> 6;

  // XCD panel-sequential remap (dispatch XCD = wg%8): XCD j processes
  // m-panels 8j..8j+7 one at a time, n inner -> A panel stays L2-resident.
  int wg = blockIdx.x + blockIdx.y * 64;
  int xcd = wg & 7;
  int idx = wg >> 3;               // 0..143
  int pp = idx / 18;               // 0..7 (panel within XCD)
  int np = idx - pp * 18;          // 0..17
  int m0 = ((xcd << 3) + pp) << 7;
  int n0 = np << 7;

  int wm = (wave >> 1) * 64;
  int wn = (wave & 1) * 64;
  int l16 = lane & 15, g = lane >> 4;

  int r8 = lane >> 3;
  int cs = (lane & 7) ^ (r8 & 7);
  const u16* gA = A  + (size_t)(m0 + wave * 32 + r8) * K + cs * 8;
  const u16* gB = Bt + (size_t)(n0 + wave * 32 + r8) * K + cs * 8;
  int lofs = wave * 2048;

  f32x4 acc[4][4];
#pragma unroll
  for (int mi = 0; mi < 4; ++mi)
#pragma unroll
    for (int ni = 0; ni < 4; ++ni) acc[mi][ni] = (f32x4){0.f, 0.f, 0.f, 0.f};

#define STAGE(Abuf, Bbuf, kk)                              \
  do {                                                     \
    gload16(gA + (kk),           Abuf + lofs);             \
    gload16(gA + (kk) +  8 * K,  Abuf + lofs + 512);       \
    gload16(gA + (kk) + 16 * K,  Abuf + lofs + 1024);      \
    gload16(gA + (kk) + 24 * K,  Abuf + lofs + 1536);      \
    gload16(gB + (kk),           Bbuf + lofs);             \
    gload16(gB + (kk) +  8 * K,  Bbuf + lofs + 512);       \
    gload16(gB + (kk) + 16 * K,  Bbuf + lofs + 1024);      \
    gload16(gB + (kk) + 24 * K,  Bbuf + lofs + 1536);      \
  } while (0)

  STAGE(as0, bs0, 0);
  STAGE(as1, bs1, 64);
  for (int j = 0; j < 5; ++j) {
    int k0 = j * 128;
    WAIT8_BAR();
    gemm_compute64(as0, bs0, wm, wn, l16, g, acc);
    BAR();
    STAGE(as0, bs0, k0 + 128);
    WAIT8_BAR();
    gemm_compute64(as1, bs1, wm, wn, l16, g, acc);
    BAR();
    STAGE(as1, bs1, k0 + 192);
  }
  WAIT8_BAR();
  gemm_compute64(as0, bs0, wm, wn, l16, g, acc);
  WAIT0_BAR();
  gemm_compute64(as1, bs1, wm, wn, l16, g, acc);
#undef STAGE

  BAR();   // lgkmcnt(0)+barrier: all LDS reads done -> smem reusable as scratch

  // epilogue. wave tile = 64 t-rows x 64 n-cols, one region & one head each.
  int tbase = m0 & 1023;
  int b = m0 >> 10;
  int nbase = n0 + wn;
  int region = nbase / 768;
  int c0 = nbase - region * 768;
  int h = c0 >> 6;
  int bh = b * 12 + h;
  int tb0 = tbase + wm;
  float scl = (region == 0) ? 0.125f : 1.0f;
  float bvs[4];
#pragma unroll
  for (int ni = 0; ni < 4; ++ni) bvs[ni] = bias[nbase + ni * 16 + l16] * scl;

  if (region == 2) {
    // vT[bh][d][t]: b64 stores along t
    int d0 = c0 & 63;
    int g4 = g * 4;
#pragma unroll
    for (int ni = 0; ni < 4; ++ni) {
      int d = d0 + ni * 16 + l16;
#pragma unroll
      for (int mi = 0; mi < 4; ++mi) {
        int t0 = tb0 + mi * 16 + g4;
        u16x4 pv;
#pragma unroll
        for (int r = 0; r < 4; ++r) pv[r] = f2bf(acc[mi][ni][r] + bvs[ni]);
        *reinterpret_cast<u16x4*>(vTb + ((size_t)bh * 64 + d) * 1024 + t0) = pv;
      }
    }
  } else {
    // q/k[bh][t][d]: transpose via per-wave LDS scratch (stride 72 -> 144B
    // rows, 16B-aligned readback), then 8 coalesced dwordx4 stores.
    u16* scr = smem + wave * (64 * 72);
    u16* dst = (region == 0) ? qb : kb;
#pragma unroll
    for (int ni = 0; ni < 4; ++ni)
#pragma unroll
      for (int mi = 0; mi < 4; ++mi)
#pragma unroll
        for (int r = 0; r < 4; ++r)
          scr[(mi * 16 + g * 4 + r) * 72 + ni * 16 + l16] =
              f2bf(fmaf(acc[mi][ni][r], scl, bvs[ni]));
    int rr = lane >> 3, cc = lane & 7;
#pragma unroll
    for (int i = 0; i < 8; ++i) {
      u16x8 v = *reinterpret_cast<const u16x8*>(scr + (i * 8 + rr) * 72 + cc * 8);
      *reinterpret_cast<u16x8*>(
          dst + ((size_t)bh * 1024 + tb0 + i * 8 + rr) * 64 + cc * 8) = v;
    }
  }
}

// ---------------- causal relu attention (block-shared K/V staging) ----------------
// y[b,h,q,:] = sum_{k<=q} relu(q.k) * v[k]   (scale pre-folded into q)
// Block = 4 waves, same head, q-groups qbase+{0,32,64,96}. K/V 64-key tiles
// staged once per block into double-buffered LDS via global_load_lds, XOR-chunk
// swizzle (both-sides). One vmcnt(0)+lgkmcnt(0)+barrier per tile.
__global__ __launch_bounds__(256, 3) void attn_kernel(
    const u16* __restrict__ qb, const u16* __restrict__ kb,
    const u16* __restrict__ vTb, float* __restrict__ out) {
  __shared__ __align__(16) u16 kbuf0[64 * 64], kbuf1[64 * 64];
  __shared__ __align__(16) u16 vbuf0[64 * 64], vbuf1[64 * 64];
  __shared__ __align__(16) u16 plds[4][32 * 72];
  int lane = threadIdx.x & 63;
  int wave = threadIdx.x >> 6;
  int bh = blockIdx.x;                           // 0..95
  int qbase = (7 - blockIdx.y) * 128;            // heaviest blocks first
  int q0 = qbase + wave * 32;
  int b = bh / 12, h = bh - b * 12;
  const u16* Q  = qb  + (size_t)bh * 65536;
  const u16* Kp = kb  + (size_t)bh * 65536;
  const u16* Vt = vTb + (size_t)bh * 65536;
  int l16 = lane & 15, g = lane >> 4;
  u16* pw = &plds[wave][0];

  int ntw = (q0 >> 6) + 1;        // this wave's active tiles
  int ntB = (qbase >> 6) + 2;     // block-uniform loop bound
  int qoff = q0 & 63;             // 0 or 32

  int r8q = lane >> 3;
  int csw = (lane & 7) ^ (r8q & 7);
  const u16* kSrc = Kp + (size_t)(wave * 16 + r8q) * 64 + csw * 8;
  const u16* vSrc = Vt + (size_t)(wave * 16 + r8q) * 1024 + csw * 8;
  int sofs = wave * 1024;

#define ASTAGE(kbuf, vbuf, kbase)                                   \
  do {                                                              \
    gload16(kSrc + (size_t)(kbase) * 64,       kbuf + sofs);        \
    gload16(kSrc + (size_t)((kbase) + 8) * 64, kbuf + sofs + 512);  \
    gload16(vSrc + (kbase),                    vbuf + sofs);        \
    gload16(vSrc + (kbase) + 8 * 1024,         vbuf + sofs + 512);  \
  } while (0)

  bf16x8 qf[2][2];
#pragma unroll
  for (int qi = 0; qi < 2; ++qi)
#pragma unroll
    for (int ks = 0; ks < 2; ++ks)
      qf[qi][ks] = __builtin_bit_cast(bf16x8,
          *reinterpret_cast<const u16x8*>(Q + (q0 + qi * 16 + l16) * 64 + ks * 32 + g * 8));

  f32x4 y[2][4];
#pragma unroll
  for (int mi = 0; mi < 2; ++mi)
#pragma unroll
    for (int ni = 0; ni < 4; ++ni) y[mi][ni] = (f32x4){0.f, 0.f, 0.f, 0.f};

  ASTAGE(kbuf0, vbuf0, 0);
  WAIT0_BAR();

  for (int kt = 0; kt < ntB; ++kt) {
    u16 *kcur, *vcur, *knx, *vnx;
    if (kt & 1) { kcur = kbuf1; vcur = vbuf1; knx = kbuf0; vnx = vbuf0; }
    else        { kcur = kbuf0; vcur = vbuf0; knx = kbuf1; vnx = vbuf1; }

    if (kt + 1 < ntB) ASTAGE(knx, vnx, (kt + 1) << 6);

    if (kt < ntw) {
      bf16x8 kf[4][2];
#pragma unroll
      for (int kj = 0; kj < 4; ++kj)
#pragma unroll
        for (int ks = 0; ks < 2; ++ks)
          kf[kj][ks] = __builtin_bit_cast(bf16x8,
              *reinterpret_cast<const u16x8*>(
                  kcur + (kj * 16 + l16) * 64 + (((ks * 4 + g) ^ (l16 & 7)) * 8)));

      f32x4 s2[4][2];
#pragma unroll
      for (int kj = 0; kj < 4; ++kj)
#pragma unroll
        for (int qi = 0; qi < 2; ++qi) s2[kj][qi] = (f32x4){0.f, 0.f, 0.f, 0.f};
      __builtin_amdgcn_s_setprio(1);
#pragma unroll
      for (int ks = 0; ks < 2; ++ks)
#pragma unroll
        for (int kj = 0; kj < 4; ++kj)
#pragma unroll
          for (int qi = 0; qi < 2; ++qi)
            s2[kj][qi] = __builtin_amdgcn_mfma_f32_16x16x32_bf16(
                kf[kj][ks], qf[qi][ks], s2[kj][qi], 0, 0, 0);
      __builtin_amdgcn_s_setprio(0);

      if (kt == ntw - 1) {
#pragma unroll
        for (int kj = 0; kj < 4; ++kj)
#pragma unroll
          for (int qi = 0; qi < 2; ++qi) {
            u16x4 pv;
#pragma unroll
            for (int r = 0; r < 4; ++r) {
              float v = fmaxf(s2[kj][qi][r], 0.f);
              if (kj * 16 + g * 4 + r > qoff + qi * 16 + l16) v = 0.f;
              pv[r] = f2bf(v);
            }
            *reinterpret_cast<u16x4*>(pw + (qi * 16 + l16) * 72 + kj * 16 + g * 4) = pv;
          }
      } else {
#pragma unroll
        for (int kj = 0; kj < 4; ++kj)
#pragma unroll
          for (int qi = 0; qi < 2; ++qi) {
            u16x4 pv;
#pragma unroll
            for (int r = 0; r < 4; ++r) pv[r] = f2bf(fmaxf(s2[kj][qi][r], 0.f));
            *reinterpret_cast<u16x4*>(pw + (qi * 16 + l16) * 72 + kj * 16 + g * 4) = pv;
          }
      }

      bf16x8 vf[4][2];
#pragma unroll
      for (int ni = 0; ni < 4; ++ni)
#pragma unroll
        for (int kc = 0; kc < 2; ++kc)
          vf[ni][kc] = __builtin_bit_cast(bf16x8,
              *reinterpret_cast<const u16x8*>(
                  vcur + (ni * 16 + l16) * 64 + (((kc * 4 + g) ^ (l16 & 7)) * 8)));

      bf16x8 pa[2][2];
#pragma unroll
      for (int mi = 0; mi < 2; ++mi)
#pragma unroll
        for (int kc = 0; kc < 2; ++kc)
          pa[mi][kc] = __builtin_bit_cast(bf16x8,
              *reinterpret_cast<const u16x8*>(pw + (mi * 16 + l16) * 72 + kc * 32 + g * 8));
      __builtin_amdgcn_s_setprio(1);
#pragma unroll
      for (int kc = 0; kc < 2; ++kc)
#pragma unroll
        for (int ni = 0; ni < 4; ++ni)
#pragma unroll
          for (int mi = 0; mi < 2; ++mi)
            y[mi][ni] = __builtin_amdgcn_mfma_f32_16x16x32_bf16(
                pa[mi][kc], vf[ni][kc], y[mi][ni], 0, 0, 0);
      __builtin_amdgcn_s_setprio(0);
    }

    WAIT0_BAR();   // vmcnt(0)+lgkmcnt(0): stage landed AND all LDS reads done
  }
#undef ASTAGE

  float* outp = out + (size_t)b * 1024 * 768 + (size_t)h * 64;
#pragma unroll
  for (int mi = 0; mi < 2; ++mi)
#pragma unroll
    for (int r = 0; r < 4; ++r) {
      int t = q0 + mi * 16 + g * 4 + r;
#pragma unroll
      for (int ni = 0; ni < 4; ++ni)
        outp[(size_t)t * 768 + ni * 16 + l16] = y[mi][ni][r];
    }
}

extern "C" void kernel_launch(void* const* d_in, const int* in_sizes, int n_in,
                              void* d_out, int out_size, void* d_ws, size_t ws_size,
                              hipStream_t stream) {
  const float* x    = (const float*)d_in[0];
  const float* W    = (const float*)d_in[1];
  const float* bias = (const float*)d_in[2];
  float* out = (float*)d_out;
  char* ws = (char*)d_ws;

  // ws layout (bytes): xb 12.58MB | WbT 3.54MB | qb 12.58MB | kb 12.58MB | vTb 12.58MB
  u16* xb  = (u16*)(ws);
  u16* WbT = (u16*)(ws + 12582912);
  u16* qb  = (u16*)(ws + 16121856);
  u16* kb  = (u16*)(ws + 28704768);
  u16* vTb = (u16*)(ws + 41287680);

  hipLaunchKernelGGL(cvt_x_kernel, dim3(3072), dim3(256), 0, stream, x, xb);
  hipLaunchKernelGGL(cvt_wT_kernel, dim3(9, 192), dim3(256), 0, stream, W, WbT);
  hipLaunchKernelGGL(gemm_qkv_kernel, dim3(64, 18), dim3(256), 0, stream,
                     xb, WbT, bias, qb, kb, vTb);
  hipLaunchKernelGGL(attn_kernel, dim3(96, 8), dim3(256), 0, stream, qb, kb, vTb, out);
}